// Round 1
// baseline (194.153 us; speedup 1.0000x reference)
//
#include <hip/hip_runtime.h>

// LJ 12-6 over a neighbor list — round 11: software-pipelined fused kernel.
// History: R2 direct-gather 131 us (walls at ~3 cyc/divergent-lane-request).
// R6 fused 4x4x4 LDS filter 91.5 us. R9 split pipeline 113 us (abandoned).
// R10 fused 6x6 xy filter (19.75% pass), NWG=256: fused kernel 74 us,
// VALUBusy 27%, HBM 17%, occupancy 36% -> latency-bound, nothing saturated.
// Occupancy is hard-capped at 1 WG/CU by the 150KB LDS table, so this round
// attacks ILP instead:
//  (a) 2-buffer software pipeline: prefetch next idx group BEFORE issuing
//      current group's gathers; filter next group between gather-issue and
//      compute (in-order vmcnt -> the filter's wait leaves gathers in
//      flight). Removes the ~300cy gather stall and most of the ~700cy idx
//      stall from the per-iteration critical path.
//  (b) cell table packed 5 atoms/word (30 bits): one aligned ds_read_b32 per
//      lookup (magic-div by 5) instead of two straddling byte reads ->
//      halves LDS filter ops + bank conflicts. Table = 160,000 B, 1 WG/CU.
//  (c) pad_R + cell merged into one prep kernel (one pass over R).

typedef int   v4i __attribute__((ext_vector_type(4)));
typedef float v4f __attribute__((ext_vector_type(4)));

#define GRP    8
#define WGT    1024
#define NWG_F  256

// ---------------- prep: pad R to float4 AND build packed cell table --------
// 5 atoms per 32-bit word, 6 bits each (cx | cy<<3, cells of size cutoff,
// clamped 0..7). Clamp is monotone -> clamped cell diff <= true diff, so the
// filter stays conservative (correct) for ANY box/cutoff.
__global__ void __launch_bounds__(256) prep_kernel(
    const float* __restrict__ R, const float* __restrict__ cut_p,
    v4f* __restrict__ Rp, unsigned* __restrict__ packed, int n_atoms)
{
    int t = blockIdx.x * blockDim.x + threadIdx.x;
    int n_grp = (n_atoms + 4) / 5;
    if (t >= n_grp) return;
    const float inv_cut = 1.0f / cut_p[0];
    int a0 = t * 5;
    unsigned w = 0u;
#pragma unroll
    for (int k = 0; k < 5; ++k) {
        int a = a0 + k;
        if (a < n_atoms) {
            float x = R[3 * a + 0];
            float y = R[3 * a + 1];
            float z = R[3 * a + 2];
            v4f v; v.x = x; v.y = y; v.z = z; v.w = 0.0f;
            Rp[a] = v;  // 16B aligned: single-transaction gathers later
            int cx = min(7, max(0, (int)(x * inv_cut)));
            int cy = min(7, max(0, (int)(y * inv_cut)));
            w |= (unsigned)(cx | (cy << 3)) << (6 * k);
        }
        // padded atoms keep cell 0 -> padded pairs (i==j==0) are rejected by
        // the r2 > 1e-10 check anyway.
    }
    packed[t] = w;
}

// standalone pad for the fallback path (ws too small for the table)
__global__ void __launch_bounds__(256) pad_R_kernel(
    const float* __restrict__ R, v4f* __restrict__ Rp, int n_atoms)
{
    int a = blockIdx.x * blockDim.x + threadIdx.x;
    if (a < n_atoms) {
        v4f v;
        v.x = R[3 * a + 0];
        v.y = R[3 * a + 1];
        v.z = R[3 * a + 2];
        v.w = 0.0f;
        Rp[a] = v;
    }
}

// one aligned ds_read_b32 per lookup: word = a/5 (magic mul), shift = (a%5)*6
__device__ __forceinline__ unsigned cell6w(const unsigned* __restrict__ lds32,
                                           unsigned a) {
    unsigned q = __umulhi(a, 0xCCCCCCCDu) >> 2;   // a / 5, exact for all u32
    unsigned r = a - q * 5u;                       // a % 5
    return (lds32[q] >> (r * 6u)) & 63u;
}

__device__ __forceinline__ void load_grp(
    const int* __restrict__ idx_i, const int* __restrict__ idx_j,
    int p, int n_pairs, int* __restrict__ is8, int* __restrict__ js8)
{
    if (p + GRP <= n_pairs) {   // p % 8 == 0 -> int4-aligned fast path
        v4i a0 = __builtin_nontemporal_load((const v4i*)idx_i + (p >> 2));
        v4i a1 = __builtin_nontemporal_load((const v4i*)idx_i + (p >> 2) + 1);
        v4i b0 = __builtin_nontemporal_load((const v4i*)idx_j + (p >> 2));
        v4i b1 = __builtin_nontemporal_load((const v4i*)idx_j + (p >> 2) + 1);
        is8[0] = a0.x; is8[1] = a0.y; is8[2] = a0.z; is8[3] = a0.w;
        is8[4] = a1.x; is8[5] = a1.y; is8[6] = a1.z; is8[7] = a1.w;
        js8[0] = b0.x; js8[1] = b0.y; js8[2] = b0.z; js8[3] = b0.w;
        js8[4] = b1.x; js8[5] = b1.y; js8[6] = b1.z; js8[7] = b1.w;
    } else {
#pragma unroll
        for (int k = 0; k < GRP; ++k) {
            bool v = (p + k < n_pairs);
            is8[k] = v ? idx_i[p + k] : 0;
            js8[k] = v ? idx_j[p + k] : 0;
            // padded entries: i==j==0 -> r2==0 -> rejected by r2>1e-10
        }
    }
}

__device__ __forceinline__ unsigned filt(const unsigned* __restrict__ lds32,
                                         const int* __restrict__ is8,
                                         const int* __restrict__ js8)
{
    unsigned m = 0u;
#pragma unroll
    for (int k = 0; k < GRP; ++k) {
        unsigned ci = cell6w(lds32, (unsigned)is8[k]);
        unsigned cj = cell6w(lds32, (unsigned)js8[k]);
        int ddx = (int)(ci & 7u) - (int)(cj & 7u);
        int ddy = (int)(ci >> 3) - (int)(cj >> 3);
        bool ok = ((unsigned)(ddx + 1) <= 2u) & ((unsigned)(ddy + 1) <= 2u);
        if (ok) m |= (1u << k);
    }
    return m;
}

__device__ __forceinline__ void lj_body(
    v4f A, v4f B, float eps, float s2, float cut2, int gi,
    float* __restrict__ energy, float* __restrict__ forces)
{
    const float dx = A.x - B.x, dy = A.y - B.y, dz = A.z - B.z;
    const float r2 = dx * dx + dy * dy + dz * dz;
    if (r2 < cut2 && r2 > 1e-10f) {
        const float inv  = 1.0f / r2;
        const float sr2  = s2 * inv;
        const float sr6  = sr2 * sr2 * sr2;
        const float sr12 = sr6 * sr6;
        const float e    = 2.0f * eps * (sr12 - sr6);              // 0.5 * 4eps
        const float f    = 24.0f * eps * (2.0f * sr12 - sr6) * inv;
        atomicAdd(&energy[gi], e);
        atomicAdd(&forces[3 * gi + 0], f * dx);
        atomicAdd(&forces[3 * gi + 1], f * dy);
        atomicAdd(&forces[3 * gi + 2], f * dz);
    }
}

// Fused, software-pipelined:
//   per iteration: [prefetch idx(n+1)] -> [masked gathers(n)] ->
//                  [filter(n+1): waits only the prefetch, gathers stay in
//                   flight (in-order vmcnt)] -> [LJ+atomics(n): waits gathers]
__global__ void __launch_bounds__(WGT) lj_fused_kernel(
    const v4f* __restrict__ Rp,
    const unsigned* __restrict__ packed,
    const int* __restrict__ idx_i,
    const int* __restrict__ idx_j,
    const float* __restrict__ eps_p,
    const float* __restrict__ sig_p,
    const float* __restrict__ cut_p,
    float* __restrict__ energy,
    float* __restrict__ forces,
    int n_pairs, int pk_words, int chunk)
{
    extern __shared__ unsigned lds[];
    for (int w = threadIdx.x; w < pk_words; w += WGT)
        lds[w] = packed[w];
    __syncthreads();

    const float eps  = eps_p[0];
    const float sig  = sig_p[0];
    const float cut  = cut_p[0];
    const float s2   = sig * sig;
    const float cut2 = cut * cut;

    const int cs = blockIdx.x * chunk;
    const int ce = min(cs + chunk, n_pairs);
    const int STRIDE = WGT * GRP;

    int p0 = cs + (int)threadIdx.x * GRP;
    if (p0 >= ce) return;

    int isA[GRP], jsA[GRP], isB[GRP], jsB[GRP];

    // prologue: load + filter group 0
    load_grp(idx_i, idx_j, p0, n_pairs, isA, jsA);
    unsigned mA = filt(lds, isA, jsA);
    int p1 = p0 + STRIDE;

    while (true) {
        const bool h1 = p1 < ce;

        // (1) prefetch next group's indices — issued first so its HBM
        //     latency overlaps everything below
        if (h1) load_grp(idx_i, idx_j, p1, n_pairs, isB, jsB);

        // (2) exec-masked gathers for current group — masked lanes issue
        //     NO requests (~19.75% pass)
        v4f Ri[GRP], Rj[GRP];
#pragma unroll
        for (int k = 0; k < GRP; ++k)
            if (mA & (1u << k)) { Ri[k] = Rp[isA[k]]; Rj[k] = Rp[jsA[k]]; }

        // (3) filter next group: waits only the (older) prefetch loads;
        //     the (newer) gathers remain outstanding
        unsigned mB = 0u;
        if (h1) mB = filt(lds, isB, jsB);

        // (4) compute + sparse atomics (~1.9% true pairs): waits gathers
#pragma unroll
        for (int k = 0; k < GRP; ++k)
            if (mA & (1u << k))
                lj_body(Ri[k], Rj[k], eps, s2, cut2, isA[k], energy, forces);

        if (!h1) break;
#pragma unroll
        for (int k = 0; k < GRP; ++k) { isA[k] = isB[k]; jsA[k] = jsB[k]; }
        mA = mB;
        p1 += STRIDE;
    }
}

// ---------- fallback (R2 structure, 131 us) if ws/LDS insufficient ----------
#define PPT 8
__global__ void __launch_bounds__(256) lj_pairs_fb_kernel(
    const v4f* __restrict__ Rp,
    const v4i* __restrict__ idx_i4, const v4i* __restrict__ idx_j4,
    const float* __restrict__ eps_p, const float* __restrict__ sig_p,
    const float* __restrict__ cut_p,
    float* __restrict__ energy, float* __restrict__ forces, int n_oct)
{
    int t = blockIdx.x * blockDim.x + threadIdx.x;
    if (t >= n_oct) return;
    const float eps  = eps_p[0];
    const float sig  = sig_p[0];
    const float cut  = cut_p[0];
    const float s2   = sig * sig;
    const float cut2 = cut * cut;
    v4i ii0 = __builtin_nontemporal_load(idx_i4 + 2 * t);
    v4i ii1 = __builtin_nontemporal_load(idx_i4 + 2 * t + 1);
    v4i jj0 = __builtin_nontemporal_load(idx_j4 + 2 * t);
    v4i jj1 = __builtin_nontemporal_load(idx_j4 + 2 * t + 1);
    int is[PPT] = { ii0.x, ii0.y, ii0.z, ii0.w, ii1.x, ii1.y, ii1.z, ii1.w };
    int js[PPT] = { jj0.x, jj0.y, jj0.z, jj0.w, jj1.x, jj1.y, jj1.z, jj1.w };
    v4f Ri[PPT], Rj[PPT];
#pragma unroll
    for (int k = 0; k < PPT; ++k) Ri[k] = Rp[is[k]];
#pragma unroll
    for (int k = 0; k < PPT; ++k) Rj[k] = Rp[js[k]];
#pragma unroll
    for (int k = 0; k < PPT; ++k)
        lj_body(Ri[k], Rj[k], eps, s2, cut2, is[k], energy, forces);
}

__global__ void lj_pairs_fb_tail_kernel(
    const v4f* __restrict__ Rp,
    const int* __restrict__ idx_i, const int* __restrict__ idx_j,
    const float* __restrict__ eps_p, const float* __restrict__ sig_p,
    const float* __restrict__ cut_p,
    float* __restrict__ energy, float* __restrict__ forces,
    int start, int n_pairs)
{
    int p = start + blockIdx.x * blockDim.x + threadIdx.x;
    if (p >= n_pairs) return;
    const float eps = eps_p[0];
    const float sig = sig_p[0];
    const float cut = cut_p[0];
    lj_body(Rp[idx_i[p]], Rp[idx_j[p]], eps, sig * sig, cut * cut,
            idx_i[p], energy, forces);
}
// -----------------------------------------------------------------------------

extern "C" void kernel_launch(void* const* d_in, const int* in_sizes, int n_in,
                              void* d_out, int out_size, void* d_ws, size_t ws_size,
                              hipStream_t stream) {
    const float* R     = (const float*)d_in[0];
    const float* eps_p = (const float*)d_in[1];
    const float* sig_p = (const float*)d_in[2];
    const float* cut_p = (const float*)d_in[3];
    const int*   idx_i = (const int*)d_in[4];
    const int*   idx_j = (const int*)d_in[5];

    const int n_atoms = in_sizes[0] / 3;
    const int n_pairs = in_sizes[4];

    float* energy = (float*)d_out;
    float* forces = (float*)d_out + n_atoms;

    // d_out re-poisoned 0xAA before every timed call — zero it.
    (void)hipMemsetAsync(d_out, 0, (size_t)out_size * sizeof(float), stream);

    // ws layout: [Rp float4][packed cell table, 5 atoms/word]
    char* ws = (char*)d_ws;
    const size_t rp_b     = (((size_t)n_atoms * 16) + 255) & ~(size_t)255;
    const int    pk_words = (n_atoms + 4) / 5;
    const size_t pk_b     = (((size_t)pk_words * 4) + 255) & ~(size_t)255;
    const size_t lds_b    = (((size_t)pk_words * 4) + 15) & ~(size_t)15;

    const bool have_rp    = ws_size >= rp_b;
    const bool use_filter = have_rp && (ws_size >= rp_b + pk_b)
                            && (lds_b <= 160000);

    v4f*      Rp     = (v4f*)ws;
    unsigned* packed = (unsigned*)(ws + rp_b);

    if (use_filter) {
        int pblocks = (pk_words + 255) / 256;
        prep_kernel<<<pblocks, 256, 0, stream>>>(R, cut_p, Rp, packed, n_atoms);

        (void)hipFuncSetAttribute((const void*)lj_fused_kernel,
                                  hipFuncAttributeMaxDynamicSharedMemorySize,
                                  (int)lds_b);

        // one WG per CU: table loaded into LDS exactly once per CU
        int chunk = (((n_pairs + NWG_F - 1) / NWG_F) + GRP - 1) & ~(GRP - 1);
        lj_fused_kernel<<<NWG_F, WGT, lds_b, stream>>>(
            Rp, packed, idx_i, idx_j, eps_p, sig_p, cut_p,
            energy, forces, n_pairs, pk_words, chunk);
    } else if (have_rp) {
        int blocks = (n_atoms + 255) / 256;
        pad_R_kernel<<<blocks, 256, 0, stream>>>(R, Rp, n_atoms);
        const int n_oct = n_pairs / PPT;
        const int start = n_oct * PPT;
        if (n_oct > 0) {
            int fblocks = (n_oct + 255) / 256;
            lj_pairs_fb_kernel<<<fblocks, 256, 0, stream>>>(
                Rp, (const v4i*)idx_i, (const v4i*)idx_j,
                eps_p, sig_p, cut_p, energy, forces, n_oct);
        }
        if (start < n_pairs) {
            lj_pairs_fb_tail_kernel<<<1, 64, 0, stream>>>(
                Rp, idx_i, idx_j, eps_p, sig_p, cut_p,
                energy, forces, start, n_pairs);
        }
    }
}

// Round 2
// 188.509 us; speedup vs baseline: 1.0299x; 1.0299x over previous
//
#include <hip/hip_runtime.h>

// LJ 12-6 over a neighbor list — round 12: pipeline with constant VMEM issue.
// History: R2 direct-gather 131 us. R6 fused 4x4x4 LDS filter 91.5 us.
// R10 fused 6x6 xy filter (19.75% pass) 74 us (VALU 27%, HBM 17%, occ 36%,
// latency-bound). R11 software pipeline REGRESSED to 79 us: VGPR stayed 64
// (launch_bounds heuristic) so the two pipeline buffers couldn't stay live,
// and exec-masked gathers made outstanding-VMEM count runtime-variable ->
// compiler forced vmcnt(0) at the filter, draining the gathers it was
// supposed to overlap. This round:
//  (a) __launch_bounds__(1024, 4): declare 4 waves/EU -> 128 VGPR budget
//      (occupancy already LDS-capped at 1 WG/CU, so nothing lost);
//  (b) filter zeroes failing indices instead of exec-masking the loads:
//      every wave issues exactly 32 gather dwordx4 per group -> counted
//      vmcnt keeps gathers in flight across the next group's filter.
//      Failing lanes gather Rp[0] (same-address broadcast ~1 extra request);
//      Rp[0]-Rp[0] -> r2=0 -> rejected by the existing r2>1e-10 check.

typedef int   v4i __attribute__((ext_vector_type(4)));
typedef float v4f __attribute__((ext_vector_type(4)));

#define GRP    8
#define WGT    1024
#define NWG_F  256

// ---------------- prep: pad R to float4 AND build packed cell table --------
// 5 atoms per 32-bit word, 6 bits each (cx | cy<<3, cells of size cutoff,
// clamped 0..7). Clamp is monotone -> clamped cell diff <= true diff, so the
// filter stays conservative (correct) for ANY box/cutoff.
__global__ void __launch_bounds__(256) prep_kernel(
    const float* __restrict__ R, const float* __restrict__ cut_p,
    v4f* __restrict__ Rp, unsigned* __restrict__ packed, int n_atoms)
{
    int t = blockIdx.x * blockDim.x + threadIdx.x;
    int n_grp = (n_atoms + 4) / 5;
    if (t >= n_grp) return;
    const float inv_cut = 1.0f / cut_p[0];
    int a0 = t * 5;
    unsigned w = 0u;
#pragma unroll
    for (int k = 0; k < 5; ++k) {
        int a = a0 + k;
        if (a < n_atoms) {
            float x = R[3 * a + 0];
            float y = R[3 * a + 1];
            float z = R[3 * a + 2];
            v4f v; v.x = x; v.y = y; v.z = z; v.w = 0.0f;
            Rp[a] = v;  // 16B aligned: single-transaction gathers later
            int cx = min(7, max(0, (int)(x * inv_cut)));
            int cy = min(7, max(0, (int)(y * inv_cut)));
            w |= (unsigned)(cx | (cy << 3)) << (6 * k);
        }
        // padded atoms keep cell 0 -> padded pairs (i==j==0) are rejected by
        // the r2 > 1e-10 check anyway.
    }
    packed[t] = w;
}

// standalone pad for the fallback path (ws too small for the table)
__global__ void __launch_bounds__(256) pad_R_kernel(
    const float* __restrict__ R, v4f* __restrict__ Rp, int n_atoms)
{
    int a = blockIdx.x * blockDim.x + threadIdx.x;
    if (a < n_atoms) {
        v4f v;
        v.x = R[3 * a + 0];
        v.y = R[3 * a + 1];
        v.z = R[3 * a + 2];
        v.w = 0.0f;
        Rp[a] = v;
    }
}

// one aligned ds_read_b32 per lookup: word = a/5 (magic mul), shift = (a%5)*6
__device__ __forceinline__ unsigned cell6w(const unsigned* __restrict__ lds32,
                                           unsigned a) {
    unsigned q = __umulhi(a, 0xCCCCCCCDu) >> 2;   // a / 5, exact for all u32
    unsigned r = a - q * 5u;                       // a % 5
    return (lds32[q] >> (r * 6u)) & 63u;
}

__device__ __forceinline__ void load_grp(
    const int* __restrict__ idx_i, const int* __restrict__ idx_j,
    int p, int n_pairs, int* __restrict__ is8, int* __restrict__ js8)
{
    if (p + GRP <= n_pairs) {   // p % 8 == 0 -> int4-aligned fast path
        v4i a0 = __builtin_nontemporal_load((const v4i*)idx_i + (p >> 2));
        v4i a1 = __builtin_nontemporal_load((const v4i*)idx_i + (p >> 2) + 1);
        v4i b0 = __builtin_nontemporal_load((const v4i*)idx_j + (p >> 2));
        v4i b1 = __builtin_nontemporal_load((const v4i*)idx_j + (p >> 2) + 1);
        is8[0] = a0.x; is8[1] = a0.y; is8[2] = a0.z; is8[3] = a0.w;
        is8[4] = a1.x; is8[5] = a1.y; is8[6] = a1.z; is8[7] = a1.w;
        js8[0] = b0.x; js8[1] = b0.y; js8[2] = b0.z; js8[3] = b0.w;
        js8[4] = b1.x; js8[5] = b1.y; js8[6] = b1.z; js8[7] = b1.w;
    } else {
#pragma unroll
        for (int k = 0; k < GRP; ++k) {
            bool v = (p + k < n_pairs);
            is8[k] = v ? idx_i[p + k] : 0;
            js8[k] = v ? idx_j[p + k] : 0;
            // padded entries: i==j==0 -> r2==0 -> rejected by r2>1e-10
        }
    }
}

// filter-and-select: failing pairs get index 0 (broadcast gather of Rp[0];
// Rp[0]-Rp[0] -> r2=0 -> rejected downstream). No exec-masked loads ->
// constant VMEM issue count -> counted vmcnt instead of vmcnt(0) drains.
__device__ __forceinline__ void filt_sel(const unsigned* __restrict__ lds32,
                                         int* __restrict__ is8,
                                         int* __restrict__ js8)
{
#pragma unroll
    for (int k = 0; k < GRP; ++k) {
        unsigned ci = cell6w(lds32, (unsigned)is8[k]);
        unsigned cj = cell6w(lds32, (unsigned)js8[k]);
        int ddx = (int)(ci & 7u) - (int)(cj & 7u);
        int ddy = (int)(ci >> 3) - (int)(cj >> 3);
        bool ok = ((unsigned)(ddx + 1) <= 2u) & ((unsigned)(ddy + 1) <= 2u);
        is8[k] = ok ? is8[k] : 0;   // v_cndmask, no branch
        js8[k] = ok ? js8[k] : 0;
    }
}

__device__ __forceinline__ void lj_body(
    v4f A, v4f B, float eps, float s2, float cut2, int gi,
    float* __restrict__ energy, float* __restrict__ forces)
{
    const float dx = A.x - B.x, dy = A.y - B.y, dz = A.z - B.z;
    const float r2 = dx * dx + dy * dy + dz * dz;
    if (r2 < cut2 && r2 > 1e-10f) {
        const float inv  = 1.0f / r2;
        const float sr2  = s2 * inv;
        const float sr6  = sr2 * sr2 * sr2;
        const float sr12 = sr6 * sr6;
        const float e    = 2.0f * eps * (sr12 - sr6);              // 0.5 * 4eps
        const float f    = 24.0f * eps * (2.0f * sr12 - sr6) * inv;
        atomicAdd(&energy[gi], e);
        atomicAdd(&forces[3 * gi + 0], f * dx);
        atomicAdd(&forces[3 * gi + 1], f * dy);
        atomicAdd(&forces[3 * gi + 2], f * dz);
    }
}

// Fused, software-pipelined, constant VMEM issue per iteration:
//   [prefetch idx(n+1): 4 loads] -> [gathers(n): 32 loads, unconditional] ->
//   [filter+select(n+1): waits vmcnt(32) -> gathers stay in flight] ->
//   [LJ+atomics(n): progressive gather waits]
__global__ void __launch_bounds__(WGT, 4) lj_fused_kernel(
    const v4f* __restrict__ Rp,
    const unsigned* __restrict__ packed,
    const int* __restrict__ idx_i,
    const int* __restrict__ idx_j,
    const float* __restrict__ eps_p,
    const float* __restrict__ sig_p,
    const float* __restrict__ cut_p,
    float* __restrict__ energy,
    float* __restrict__ forces,
    int n_pairs, int pk_words, int chunk)
{
    extern __shared__ unsigned lds[];
    for (int w = threadIdx.x; w < pk_words; w += WGT)
        lds[w] = packed[w];
    __syncthreads();

    const float eps  = eps_p[0];
    const float sig  = sig_p[0];
    const float cut  = cut_p[0];
    const float s2   = sig * sig;
    const float cut2 = cut * cut;

    const int cs = blockIdx.x * chunk;
    const int ce = min(cs + chunk, n_pairs);
    const int STRIDE = WGT * GRP;

    int p0 = cs + (int)threadIdx.x * GRP;
    if (p0 >= ce) return;

    int isA[GRP], jsA[GRP], isB[GRP], jsB[GRP];

    // prologue: load + filter group 0
    load_grp(idx_i, idx_j, p0, n_pairs, isA, jsA);
    filt_sel(lds, isA, jsA);
    int p1 = p0 + STRIDE;

    while (true) {
        const bool h1 = p1 < ce;

        // (1) prefetch next group's indices — issued first so its HBM
        //     latency overlaps everything below
        if (h1) load_grp(idx_i, idx_j, p1, n_pairs, isB, jsB);

        // (2) gathers for current group — unconditional issue; filtered
        //     pairs hit Rp[0] (same-address broadcast, ~1 extra request)
        v4f Ri[GRP], Rj[GRP];
#pragma unroll
        for (int k = 0; k < GRP; ++k) { Ri[k] = Rp[isA[k]]; Rj[k] = Rp[jsA[k]]; }

        // (3) filter+select next group: waits only the (older) prefetch
        //     loads via counted vmcnt; the 32 gathers remain outstanding
        if (h1) filt_sel(lds, isB, jsB);

        // (4) compute + sparse atomics (~1.9% true pairs): waits gathers
#pragma unroll
        for (int k = 0; k < GRP; ++k)
            lj_body(Ri[k], Rj[k], eps, s2, cut2, isA[k], energy, forces);

        if (!h1) break;
#pragma unroll
        for (int k = 0; k < GRP; ++k) { isA[k] = isB[k]; jsA[k] = jsB[k]; }
        p1 += STRIDE;
    }
}

// ---------- fallback (R2 structure, 131 us) if ws/LDS insufficient ----------
#define PPT 8
__global__ void __launch_bounds__(256) lj_pairs_fb_kernel(
    const v4f* __restrict__ Rp,
    const v4i* __restrict__ idx_i4, const v4i* __restrict__ idx_j4,
    const float* __restrict__ eps_p, const float* __restrict__ sig_p,
    const float* __restrict__ cut_p,
    float* __restrict__ energy, float* __restrict__ forces, int n_oct)
{
    int t = blockIdx.x * blockDim.x + threadIdx.x;
    if (t >= n_oct) return;
    const float eps  = eps_p[0];
    const float sig  = sig_p[0];
    const float cut  = cut_p[0];
    const float s2   = sig * sig;
    const float cut2 = cut * cut;
    v4i ii0 = __builtin_nontemporal_load(idx_i4 + 2 * t);
    v4i ii1 = __builtin_nontemporal_load(idx_i4 + 2 * t + 1);
    v4i jj0 = __builtin_nontemporal_load(idx_j4 + 2 * t);
    v4i jj1 = __builtin_nontemporal_load(idx_j4 + 2 * t + 1);
    int is[PPT] = { ii0.x, ii0.y, ii0.z, ii0.w, ii1.x, ii1.y, ii1.z, ii1.w };
    int js[PPT] = { jj0.x, jj0.y, jj0.z, jj0.w, jj1.x, jj1.y, jj1.z, jj1.w };
    v4f Ri[PPT], Rj[PPT];
#pragma unroll
    for (int k = 0; k < PPT; ++k) Ri[k] = Rp[is[k]];
#pragma unroll
    for (int k = 0; k < PPT; ++k) Rj[k] = Rp[js[k]];
#pragma unroll
    for (int k = 0; k < PPT; ++k)
        lj_body(Ri[k], Rj[k], eps, s2, cut2, is[k], energy, forces);
}

__global__ void lj_pairs_fb_tail_kernel(
    const v4f* __restrict__ Rp,
    const int* __restrict__ idx_i, const int* __restrict__ idx_j,
    const float* __restrict__ eps_p, const float* __restrict__ sig_p,
    const float* __restrict__ cut_p,
    float* __restrict__ energy, float* __restrict__ forces,
    int start, int n_pairs)
{
    int p = start + blockIdx.x * blockDim.x + threadIdx.x;
    if (p >= n_pairs) return;
    const float eps = eps_p[0];
    const float sig = sig_p[0];
    const float cut = cut_p[0];
    lj_body(Rp[idx_i[p]], Rp[idx_j[p]], eps, sig * sig, cut * cut,
            idx_i[p], energy, forces);
}
// -----------------------------------------------------------------------------

extern "C" void kernel_launch(void* const* d_in, const int* in_sizes, int n_in,
                              void* d_out, int out_size, void* d_ws, size_t ws_size,
                              hipStream_t stream) {
    const float* R     = (const float*)d_in[0];
    const float* eps_p = (const float*)d_in[1];
    const float* sig_p = (const float*)d_in[2];
    const float* cut_p = (const float*)d_in[3];
    const int*   idx_i = (const int*)d_in[4];
    const int*   idx_j = (const int*)d_in[5];

    const int n_atoms = in_sizes[0] / 3;
    const int n_pairs = in_sizes[4];

    float* energy = (float*)d_out;
    float* forces = (float*)d_out + n_atoms;

    // d_out re-poisoned 0xAA before every timed call — zero it.
    (void)hipMemsetAsync(d_out, 0, (size_t)out_size * sizeof(float), stream);

    // ws layout: [Rp float4][packed cell table, 5 atoms/word]
    char* ws = (char*)d_ws;
    const size_t rp_b     = (((size_t)n_atoms * 16) + 255) & ~(size_t)255;
    const int    pk_words = (n_atoms + 4) / 5;
    const size_t pk_b     = (((size_t)pk_words * 4) + 255) & ~(size_t)255;
    const size_t lds_b    = (((size_t)pk_words * 4) + 15) & ~(size_t)15;

    const bool have_rp    = ws_size >= rp_b;
    const bool use_filter = have_rp && (ws_size >= rp_b + pk_b)
                            && (lds_b <= 160000);

    v4f*      Rp     = (v4f*)ws;
    unsigned* packed = (unsigned*)(ws + rp_b);

    if (use_filter) {
        int pblocks = (pk_words + 255) / 256;
        prep_kernel<<<pblocks, 256, 0, stream>>>(R, cut_p, Rp, packed, n_atoms);

        (void)hipFuncSetAttribute((const void*)lj_fused_kernel,
                                  hipFuncAttributeMaxDynamicSharedMemorySize,
                                  (int)lds_b);

        // one WG per CU: table loaded into LDS exactly once per CU
        int chunk = (((n_pairs + NWG_F - 1) / NWG_F) + GRP - 1) & ~(GRP - 1);
        lj_fused_kernel<<<NWG_F, WGT, lds_b, stream>>>(
            Rp, packed, idx_i, idx_j, eps_p, sig_p, cut_p,
            energy, forces, n_pairs, pk_words, chunk);
    } else if (have_rp) {
        int blocks = (n_atoms + 255) / 256;
        pad_R_kernel<<<blocks, 256, 0, stream>>>(R, Rp, n_atoms);
        const int n_oct = n_pairs / PPT;
        const int start = n_oct * PPT;
        if (n_oct > 0) {
            int fblocks = (n_oct + 255) / 256;
            lj_pairs_fb_kernel<<<fblocks, 256, 0, stream>>>(
                Rp, (const v4i*)idx_i, (const v4i*)idx_j,
                eps_p, sig_p, cut_p, energy, forces, n_oct);
        }
        if (start < n_pairs) {
            lj_pairs_fb_tail_kernel<<<1, 64, 0, stream>>>(
                Rp, idx_i, idx_j, eps_p, sig_p, cut_p,
                energy, forces, start, n_pairs);
        }
    }
}